// Round 11
// baseline (80.475 us; speedup 1.0000x reference)
//
#include <hip/hip_runtime.h>

#define LOG2E 1.4426950408889634f
#define TWO_LOG2E 2.885390081777927f

__device__ __forceinline__ float fast_exp2(float x) { return __builtin_amdgcn_exp2f(x); }
__device__ __forceinline__ float fast_rcp(float x)  { return __builtin_amdgcn_rcpf(x); }

// ---------------------------------------------------------------------------
// K1: projections + exp transform. Virtual M=4096 rows: blocks 0..255 ->
// exp2(2*log2e * query*Wq) -> eq, blocks 256..511 -> value*Wv -> ek.
// ---------------------------------------------------------------------------
__global__ __launch_bounds__(256) void proj_kernel(
    const float* __restrict__ query, const float* __restrict__ value,
    const float* __restrict__ Wq, const float* __restrict__ Wv,
    float* __restrict__ eq, float* __restrict__ ek)
{
    __shared__ float in_lds[8 * 256];
    const int t = threadIdx.x;
    const int row0 = blockIdx.x * 8;
    const float* src; const float* W; float* dst;
    if (row0 < 2048) { src = query + (size_t)row0 * 256; W = Wq; dst = eq + (size_t)row0 * 256; }
    else { const int r = row0 - 2048; src = value + (size_t)r * 256; W = Wv; dst = ek + (size_t)r * 256; }

    const float4* s4 = (const float4*)src;
    float4* l4 = (float4*)in_lds;
    l4[t] = s4[t];
    l4[t + 256] = s4[t + 256];
    __syncthreads();

    float acc[8];
#pragma unroll
    for (int r = 0; r < 8; ++r) acc[r] = 0.f;

    for (int d = 0; d < 256; d += 4) {
        const float w0 = W[(d + 0) * 256 + t];
        const float w1 = W[(d + 1) * 256 + t];
        const float w2 = W[(d + 2) * 256 + t];
        const float w3 = W[(d + 3) * 256 + t];
#pragma unroll
        for (int r = 0; r < 8; ++r) {
            const float4 v = *(const float4*)&in_lds[r * 256 + d];
            acc[r] = fmaf(v.x, w0, acc[r]);
            acc[r] = fmaf(v.y, w1, acc[r]);
            acc[r] = fmaf(v.z, w2, acc[r]);
            acc[r] = fmaf(v.w, w3, acc[r]);
        }
    }
#pragma unroll
    for (int r = 0; r < 8; ++r) dst[r * 256 + t] = fast_exp2(acc[r] * TWO_LOG2E);
}

// ---------------------------------------------------------------------------
// K2: FUSED scores + softmax + PV (flash-style, one pass over k-tiles).
// Block = (b, 8 q-rows), 512 thr (8 waves), grid (64,4) = 256 blocks (1/CU).
//   score*[q,k] = sum_d (-2*scale[d]) / (eq*ek + 1)  (constant shift vs true
//   score; softmax cancels). Paired-rcp: 1 rcp per 2 d-terms (10 cyc/elem).
// Phase A: 8 k-tiles of 64 rows; stage ek tile (stride 258: b64 reads 2-way
//   = free); thread = (q=wave w, k=64*tt+lane); tt fully unrolled so e[8]
//   stays in registers.
// Phase B: register softmax (shfl_xor), ONE normalized attn write, raw exp
//   -> s_lds, inv -> inv_lds.
// Phase C: PV. Wave w owns k in [64w,64w+64): coalesced global value loads
//   (L2-resident), uniform b128 s_lds reads, acc[8] float4.
// Phase D: cross-wave tree reduce in LDS overlaid on ek tile buffer.
// LDS ~92KB -> 1 block/CU.
// ---------------------------------------------------------------------------
#define EK_ST 258
#define EQ_ST 258
#define SS_ROW 516
__global__ __launch_bounds__(512) void fused_kernel(
    const float* __restrict__ eq, const float* __restrict__ ek,
    const float* __restrict__ scale, const float* __restrict__ value,
    float* __restrict__ attn, float* __restrict__ out)
{
    __shared__ float ek_lds[64 * EK_ST];   // 66KB; overlaid as reduce buffer in D
    __shared__ float eq_lds[8 * EQ_ST];
    __shared__ float sc_lds[256];
    __shared__ float s_lds[8 * SS_ROW];
    __shared__ float inv_lds[8];

    const int t = threadIdx.x;
    const int w = t >> 6, lane = t & 63;
    const int qt = blockIdx.x, b = blockIdx.y;
    const int q0 = qt * 8;

    // stage eq (8 rows x 256) and scale
    {
        const float4 v = *((const float4*)(eq + (size_t)(b * 512 + q0) * 256) + t);
        const int row = t >> 6, c4 = (t & 63) * 4;
        *(float2*)&eq_lds[row * EQ_ST + c4]     = make_float2(v.x, v.y);
        *(float2*)&eq_lds[row * EQ_ST + c4 + 2] = make_float2(v.z, v.w);
    }
    if (t < 256) sc_lds[t] = -2.f * scale[t];

    float e[8];
    const float* ekb = ek + (size_t)(b * 512) * 256;

    // ---- Phase A: scores over 8 k-tiles ----
#pragma unroll
    for (int tt = 0; tt < 8; ++tt) {
        __syncthreads();
        const float4* src = (const float4*)(ekb + (size_t)(64 * tt) * 256);
#pragma unroll
        for (int l = 0; l < 8; ++l) {
            const int idx = t + 512 * l;               // 0..4095 float4s
            const int row = idx >> 6, c4 = (idx & 63) * 4;
            const float4 v = src[idx];
            *(float2*)&ek_lds[row * EK_ST + c4]     = make_float2(v.x, v.y);
            *(float2*)&ek_lds[row * EK_ST + c4 + 2] = make_float2(v.z, v.w);
        }
        __syncthreads();

        float acc = 0.f;
        const float* eqrow = &eq_lds[w * EQ_ST];
        const float* ekrow = &ek_lds[lane * EK_ST];
#pragma unroll 4
        for (int d = 0; d < 256; d += 2) {
            const float2 s2 = *(const float2*)&sc_lds[d];
            const float2 qv = *(const float2*)&eqrow[d];
            const float2 kv = *(const float2*)&ekrow[d];
            const float A = fmaf(qv.x, kv.x, 1.f);
            const float B = fmaf(qv.y, kv.y, 1.f);
            acc = fmaf(fmaf(s2.y, A, s2.x * B), fast_rcp(A * B), acc);
        }
        e[tt] = acc;                                    // k = 64*tt + lane
    }

    // ---- Phase B: softmax (wave w = q-row w), attn write ----
    float m = -1e30f;
#pragma unroll
    for (int j = 0; j < 8; ++j) m = fmaxf(m, e[j]);
#pragma unroll
    for (int off = 32; off; off >>= 1) m = fmaxf(m, __shfl_xor(m, off));

    float sum = 0.f;
#pragma unroll
    for (int j = 0; j < 8; ++j) { e[j] = fast_exp2((e[j] - m) * LOG2E); sum += e[j]; }
#pragma unroll
    for (int off = 32; off; off >>= 1) sum += __shfl_xor(sum, off);
    const float inv = fast_rcp(sum);

    float* arow = attn + (size_t)(b * 512 + q0 + w) * 512;
#pragma unroll
    for (int j = 0; j < 8; ++j) {
        s_lds[w * SS_ROW + 64 * j + lane] = e[j];
        arow[64 * j + lane] = e[j] * inv;
    }
    if (lane == 0) inv_lds[w] = inv;
    __syncthreads();

    // ---- Phase C: PV, wave w covers k in [64w, 64w+64) ----
    float4 acc[8];
#pragma unroll
    for (int r = 0; r < 8; ++r) acc[r] = make_float4(0.f, 0.f, 0.f, 0.f);

    const float* vbase = value + (size_t)(b * 512 + 64 * w) * 256;
    for (int k4 = 0; k4 < 64; k4 += 4) {
        const float4 v0 = *(const float4*)&vbase[(k4 + 0) * 256 + lane * 4];
        const float4 v1 = *(const float4*)&vbase[(k4 + 1) * 256 + lane * 4];
        const float4 v2 = *(const float4*)&vbase[(k4 + 2) * 256 + lane * 4];
        const float4 v3 = *(const float4*)&vbase[(k4 + 3) * 256 + lane * 4];
#pragma unroll
        for (int r = 0; r < 8; ++r) {
            const float4 s4 = *(const float4*)&s_lds[r * SS_ROW + 64 * w + k4];
            acc[r].x = fmaf(s4.x, v0.x, acc[r].x); acc[r].y = fmaf(s4.x, v0.y, acc[r].y);
            acc[r].z = fmaf(s4.x, v0.z, acc[r].z); acc[r].w = fmaf(s4.x, v0.w, acc[r].w);
            acc[r].x = fmaf(s4.y, v1.x, acc[r].x); acc[r].y = fmaf(s4.y, v1.y, acc[r].y);
            acc[r].z = fmaf(s4.y, v1.z, acc[r].z); acc[r].w = fmaf(s4.y, v1.w, acc[r].w);
            acc[r].x = fmaf(s4.z, v2.x, acc[r].x); acc[r].y = fmaf(s4.z, v2.y, acc[r].y);
            acc[r].z = fmaf(s4.z, v2.z, acc[r].z); acc[r].w = fmaf(s4.z, v2.w, acc[r].w);
            acc[r].x = fmaf(s4.w, v3.x, acc[r].x); acc[r].y = fmaf(s4.w, v3.y, acc[r].y);
            acc[r].z = fmaf(s4.w, v3.z, acc[r].z); acc[r].w = fmaf(s4.w, v3.w, acc[r].w);
        }
    }

    // ---- Phase D: cross-wave tree reduce (red overlaid on ek_lds) ----
    float* red = ek_lds;                     // 32KB needed <= 66KB available
    if (w >= 4) {
#pragma unroll
        for (int r = 0; r < 8; ++r)
            *(float4*)&red[((w - 4) * 8 + r) * 256 + lane * 4] = acc[r];
    }
    __syncthreads();
    if (w < 4) {
#pragma unroll
        for (int r = 0; r < 8; ++r) {
            const float4 o = *(const float4*)&red[(w * 8 + r) * 256 + lane * 4];
            acc[r].x += o.x; acc[r].y += o.y; acc[r].z += o.z; acc[r].w += o.w;
        }
    }
    __syncthreads();
    if (w >= 2 && w < 4) {
#pragma unroll
        for (int r = 0; r < 8; ++r)
            *(float4*)&red[((w - 2) * 8 + r) * 256 + lane * 4] = acc[r];
    }
    __syncthreads();
    if (w < 2) {
#pragma unroll
        for (int r = 0; r < 8; ++r) {
            const float4 o = *(const float4*)&red[(w * 8 + r) * 256 + lane * 4];
            acc[r].x += o.x; acc[r].y += o.y; acc[r].z += o.z; acc[r].w += o.w;
        }
    }
    __syncthreads();
    if (w == 1) {
#pragma unroll
        for (int r = 0; r < 8; ++r)
            *(float4*)&red[r * 256 + lane * 4] = acc[r];
    }
    __syncthreads();
    if (w == 0) {
#pragma unroll
        for (int r = 0; r < 8; ++r) {
            const float4 o = *(const float4*)&red[r * 256 + lane * 4];
            const float iv = inv_lds[r];
            float4 res;
            res.x = (acc[r].x + o.x) * iv;
            res.y = (acc[r].y + o.y) * iv;
            res.z = (acc[r].z + o.z) * iv;
            res.w = (acc[r].w + o.w) * iv;
            *(float4*)&out[(size_t)(b * 512 + q0 + r) * 256 + lane * 4] = res;
        }
    }
}

extern "C" void kernel_launch(void* const* d_in, const int* in_sizes, int n_in,
                              void* d_out, int out_size, void* d_ws, size_t ws_size,
                              hipStream_t stream) {
    const float* query = (const float*)d_in[0];
    const float* value = (const float*)d_in[1];
    const float* Wq    = (const float*)d_in[2];
    const float* Wv    = (const float*)d_in[3];
    const float* scale = (const float*)d_in[4];

    float* out0 = (float*)d_out;                 // [4,512,256]
    float* attn = out0 + 4 * 512 * 256;          // [4,512,512]

    float* eq = (float*)d_ws;                    // [2048,256]
    float* ek = eq + 2048 * 256;                 // [2048,256]

    proj_kernel<<<512, 256, 0, stream>>>(query, value, Wq, Wv, eq, ek);
    fused_kernel<<<dim3(64, 4), 512, 0, stream>>>(eq, ek, scale, value, attn, out0);
}